// Round 4
// baseline (391.267 us; speedup 1.0000x reference)
//
#include <hip/hip_runtime.h>

typedef __attribute__((ext_vector_type(4))) float f32x4;
typedef __attribute__((ext_vector_type(8))) short bf16x8;
typedef __attribute__((ext_vector_type(4))) unsigned short us4;
typedef unsigned short ushort_t;

__device__ __forceinline__ float bf2f(ushort_t u){
  union { unsigned int i; float f; } v; v.i = ((unsigned int)u) << 16; return v.f;
}
__device__ __forceinline__ ushort_t f2bf(float f){
  union { float f; unsigned int i; } v; v.f = f;
  unsigned int r = v.i + 0x7fffu + ((v.i >> 16) & 1u);
  return (ushort_t)(r >> 16);
}
__device__ __forceinline__ void async16(const ushort_t* g, ushort_t* l){
  __builtin_amdgcn_global_load_lds(
      (const __attribute__((address_space(1))) unsigned int*)g,
      (__attribute__((address_space(3))) unsigned int*)l, 16, 0, 0);
}

// ---------------------------------------------------------------------------
// Dtype detection (f32 vs bf16 inputs) — unchanged (validated).
// ---------------------------------------------------------------------------
__global__ void detect_f32(const ushort_t* __restrict__ probe, int* __restrict__ flag){
  const int lane = threadIdx.x;
  int big = 0;
  for (int i = lane; i < 4096; i += 64) {
    const int ex = (probe[i] >> 7) & 0xFF;
    if (ex >= 0x90) big++;
  }
#pragma unroll
  for (int off = 32; off > 0; off >>= 1) big += __shfl_xor(big, off);
  if (lane == 0) *flag = (big > 16) ? 1 : 0;
}

// ---------------------------------------------------------------------------
// One fused convert for all 7 inputs.
// ---------------------------------------------------------------------------
__global__ __launch_bounds__(256) void convert_all(
    const void* s0, const void* s1, const void* s2, const void* s3,
    const void* s4, const void* s5, const void* s6,
    ushort_t* d0, ushort_t* d1, ushort_t* d2, ushort_t* d3,
    ushort_t* d4, ushort_t* d5, ushort_t* d6,
    const int* __restrict__ flag)
{
  long i = ((long)blockIdx.x * 256 + threadIdx.x) * 4;
  if (i >= 18874624L) return;
  const void* src; ushort_t* dst; long loc;
  if      (i <  8388608L) { src = s0; dst = d0; loc = i; }
  else if (i < 12582912L) { src = s1; dst = d1; loc = i - 8388608L; }
  else if (i < 13631488L) { src = s2; dst = d2; loc = i - 12582912L; }
  else if (i < 14680064L) { src = s3; dst = d3; loc = i - 13631488L; }
  else if (i < 18874368L) { src = s4; dst = d4; loc = i - 14680064L; }
  else if (i < 18874496L) { src = s5; dst = d5; loc = i - 18874368L; }
  else                    { src = s6; dst = d6; loc = i - 18874496L; }
  if (*flag != 0) {
    f32x4 v = *(const f32x4*)((const float*)src + loc);
    us4 o; o[0] = f2bf(v[0]); o[1] = f2bf(v[1]); o[2] = f2bf(v[2]); o[3] = f2bf(v[3]);
    *(us4*)(dst + loc) = o;
  } else {
    *(us4*)(dst + loc) = *(const us4*)((const ushort_t*)src + loc);
  }
}

// ---------------------------------------------------------------------------
// Fused QKV GEMM (unchanged from round 3; V region writes V^T layout).
// ---------------------------------------------------------------------------
#define BK 64
__global__ __launch_bounds__(256) void qkv_gemm(
    const ushort_t* __restrict__ A,
    const ushort_t* __restrict__ Wq, const ushort_t* __restrict__ Wk,
    const ushort_t* __restrict__ Wv,
    ushort_t* __restrict__ Q, ushort_t* __restrict__ Kb, ushort_t* __restrict__ Vt)
{
  __shared__ __align__(16) ushort_t As[128*BK];
  __shared__ __align__(16) ushort_t Bs[128*BK];
  const int tid = threadIdx.x;
  const int lane = tid & 63, wave = tid >> 6;
  const int quad = lane >> 4, l16 = lane & 15;
  const int m0 = blockIdx.y * 128;
  const int n0g = blockIdx.x * 128;
  const ushort_t* B; int n0, mode;
  if      (n0g < 2048) { B = Wq; n0 = n0g;        mode = 0; }
  else if (n0g < 2560) { B = Wk; n0 = n0g - 2048; mode = 1; }
  else                 { B = Wv; n0 = n0g - 2560; mode = 2; }
  const int wm = (wave >> 1) * 64, wn = (wave & 1) * 64;
  const int srow = lane >> 3, sslot = lane & 7;

  f32x4 acc[4][4];
#pragma unroll
  for (int i = 0; i < 4; i++)
#pragma unroll
    for (int j = 0; j < 4; j++) acc[i][j] = (f32x4){0.f,0.f,0.f,0.f};

  for (int k0 = 0; k0 < 2048; k0 += BK) {
    __syncthreads();
#pragma unroll
    for (int i = 0; i < 4; i++) {
      const int r0 = wave*32 + i*8;
      const int row = r0 + srow;
      const int g = (sslot ^ (row & 7)) * 8;
      async16(A + (size_t)(m0 + row)*2048 + k0 + g, &As[r0*64]);
      async16(B + (size_t)(n0 + row)*2048 + k0 + g, &Bs[r0*64]);
    }
    __syncthreads();
#pragma unroll
    for (int kc = 0; kc < 2; kc++) {
      bf16x8 af[4], bfr[4];
#pragma unroll
      for (int i = 0; i < 4; i++) {
        const int ra = wm + i*16 + l16;
        af[i] = *(const bf16x8*)&As[ra*64 + (((kc*4 + quad) ^ (ra & 7)))*8];
        const int rb = wn + i*16 + l16;
        bfr[i] = *(const bf16x8*)&Bs[rb*64 + (((kc*4 + quad) ^ (rb & 7)))*8];
      }
#pragma unroll
      for (int i = 0; i < 4; i++)
#pragma unroll
        for (int j = 0; j < 4; j++)
          acc[i][j] = __builtin_amdgcn_mfma_f32_16x16x32_bf16(af[i], bfr[j], acc[i][j], 0, 0, 0);
    }
  }
#pragma unroll
  for (int i = 0; i < 4; i++) {
    const int rbase = m0 + wm + i*16 + quad*4;
#pragma unroll
    for (int j = 0; j < 4; j++) {
      const int col = n0 + wn + j*16 + l16;
      if (mode == 0) {
#pragma unroll
        for (int r = 0; r < 4; r++) Q[(size_t)(rbase + r)*2048 + col] = f2bf(acc[i][j][r]);
      } else if (mode == 1) {
#pragma unroll
        for (int r = 0; r < 4; r++) Kb[(size_t)(rbase + r)*512 + col] = f2bf(acc[i][j][r]);
      } else {
        us4 pk;
#pragma unroll
        for (int r = 0; r < 4; r++) pk[r] = f2bf(acc[i][j][r]);
        const size_t addr = (size_t)((rbase >> 11)*512 + col)*2048 + (rbase & 2047);
        *(us4*)&Vt[addr] = pk;
      }
    }
  }
}

// ---------------------------------------------------------------------------
// Per-128-dim RMSNorm in place (K). bf16x8 per lane: 4 rows/wave.
// ---------------------------------------------------------------------------
__global__ __launch_bounds__(256) void rmsnorm_rows(
    ushort_t* __restrict__ buf, const ushort_t* __restrict__ gamma)
{
  const int lane = threadIdx.x & 63, wave = threadIdx.x >> 6;
  const int quad = lane >> 4, l16 = lane & 15;
  const int vec = blockIdx.x*16 + wave*4 + quad;
  const size_t base = (size_t)vec*128 + l16*8;
  bf16x8 v = *(const bf16x8*)&buf[base];
  float f[8]; float ss = 0.f;
#pragma unroll
  for (int j = 0; j < 8; j++) { f[j] = bf2f((ushort_t)v[j]); ss += f[j]*f[j]; }
#pragma unroll
  for (int off = 1; off < 16; off <<= 1) ss += __shfl_xor(ss, off);
  const float sc = rsqrtf(ss * (1.0f/128.0f) + 1e-6f);
  bf16x8 g = *(const bf16x8*)&gamma[l16*8];
  bf16x8 o;
#pragma unroll
  for (int j = 0; j < 8; j++) o[j] = (short)f2bf(f[j]*sc*bf2f((ushort_t)g[j]));
  *(bf16x8*)&buf[base] = o;
}

// ---------------------------------------------------------------------------
// Flash attention, S^T orientation. Single-buffered LDS (41 KB -> 3 blocks/CU)
// with register prefetch of tile kb+1. Raw s_barrier (lgkm-only wait) keeps
// the prefetch in flight across the "readers done" barrier; the ds_write's
// own vmcnt dependency lands after a full compute phase. Softcap+exp fused
// into one v_exp: |score| <= 128*scale = 11.32 so tanh arg <= 0.227 -> 3-term
// Taylor, log2e folded into coefficients.
// ---------------------------------------------------------------------------
__global__ __launch_bounds__(256, 3) void attn_fused(
    const ushort_t* __restrict__ qbuf, const ushort_t* __restrict__ kbuf,
    const ushort_t* __restrict__ vtbuf, const ushort_t* __restrict__ qgamma,
    ushort_t* __restrict__ obuf)
{
  __shared__ __align__(16) ushort_t Ks[64*128];    // [key][dim], swizzled
  __shared__ __align__(16) ushort_t VTs[128*64];   // [dim][key], swizzled
  __shared__ __align__(16) ushort_t Ps[4][16*72];  // per-wave P [qrow][64+pad]
  const int tid = threadIdx.x;
  const int lane = tid & 63, wave = tid >> 6;
  const int quad = lane >> 4, l16 = lane & 15;
  const int bx = 31 - blockIdx.x;          // longest blocks dispatch first
  const int h = blockIdx.y, b = blockIdx.z;
  const int kvh = h >> 2;
  const size_t bT = (size_t)b * 2048;
  const int qrow = bx*64 + wave*16 + l16;
  const size_t vbase = ((size_t)(b*4 + kvh)) * 128 * 2048;

  // ---- Q load + fused RMSNorm (gamma + 1/sqrt(HD) folded in) ----
  const ushort_t* qptr = qbuf + (bT + qrow)*2048 + h*128;
  float qv[4][8];
  float ss = 0.f;
#pragma unroll
  for (int kc = 0; kc < 4; kc++) {
    bf16x8 v = *(const bf16x8*)&qptr[kc*32 + quad*8];
#pragma unroll
    for (int j = 0; j < 8; j++) { float f = bf2f((ushort_t)v[j]); qv[kc][j] = f; ss += f*f; }
  }
  ss += __shfl_xor(ss, 16);
  ss += __shfl_xor(ss, 32);
  const float qsc = rsqrtf(ss*(1.0f/128.0f) + 1e-6f) * 0.08838834764831845f;
  bf16x8 qf[4];
#pragma unroll
  for (int kc = 0; kc < 4; kc++) {
    bf16x8 g = *(const bf16x8*)&qgamma[kc*32 + quad*8];
    bf16x8 o;
#pragma unroll
    for (int j = 0; j < 8; j++) o[j] = (short)f2bf(qv[kc][j] * qsc * bf2f((ushort_t)g[j]));
    qf[kc] = o;
  }

  f32x4 Ob[8];
#pragma unroll
  for (int i = 0; i < 8; i++) Ob[i] = (f32x4){0.f,0.f,0.f,0.f};
  float l_run = 0.f;

  // ---- staging: global->reg prefetch, reg->LDS write (same swizzle as the
  //      round-3 async16 layout: LDS[row][c] holds global chunk c^(row&mask))
  const ushort_t* kg0 = kbuf + (bT + wave*16 + (lane>>4))*512 + kvh*128;
  const ushort_t* vg0 = vtbuf + vbase + (size_t)(wave*32 + (lane>>3))*2048;
  bf16x8 kreg[4], vreg[4];
  auto loadKV = [&](int kb){
#pragma unroll
    for (int i = 0; i < 4; i++) {
      const int sw = ((lane & 15) ^ ((i*4 + (lane>>4)) & 15)) * 8;
      kreg[i] = *(const bf16x8*)(kg0 + (size_t)(kb*64 + i*4)*512 + sw);
    }
#pragma unroll
    for (int i = 0; i < 4; i++) {
      const int sw = ((lane & 7) ^ ((i*8 + (lane>>3)) & 7)) * 8;
      vreg[i] = *(const bf16x8*)(vg0 + (size_t)(i*8)*2048 + kb*64 + sw);
    }
  };
  auto writeKV = [&](){
#pragma unroll
    for (int i = 0; i < 4; i++)
      *(bf16x8*)&Ks[(wave*16 + i*4)*128 + lane*8] = kreg[i];
#pragma unroll
    for (int i = 0; i < 4; i++)
      *(bf16x8*)&VTs[(wave*32 + i*8)*64 + lane*8] = vreg[i];
  };

  loadKV(0);
  writeKV();
  __syncthreads();

  for (int kb = 0; kb <= bx; kb++) {
    const bool last = (kb == bx);
    if (!last) loadKV(kb+1);           // in flight across the whole compute

    // ---- S^T = K · Q^T (addresses loop-invariant: single buffer) ----
    f32x4 st[4];
#pragma unroll
    for (int s = 0; s < 4; s++) {
      f32x4 c = (f32x4){0.f,0.f,0.f,0.f};
#pragma unroll
      for (int kc = 0; kc < 4; kc++) {
        const int row = s*16 + l16;
        const bf16x8 kf = *(const bf16x8*)&Ks[row*128 + (((kc*4 + quad) ^ (row & 15)))*8];
        c = __builtin_amdgcn_mfma_f32_16x16x32_bf16(kf, qf[kc], c, 0, 0, 0);
      }
      st[s] = c;
    }

    // softcap+softmax in one v_exp: p = exp2(x*(c0 + c1*w + c2*w^2)), w = x^2
    const int myq = wave*16 + l16;
    float rsum = 0.f;
#pragma unroll
    for (int s = 0; s < 4; s++) {
      us4 pk;
#pragma unroll
      for (int r = 0; r < 4; r++) {
        const float x = st[s][r];
        const float w = x*x;
        const float t2 = x * __builtin_fmaf(w,
            __builtin_fmaf(w, 3.0777494e-8f, -1.9235934e-4f), 1.4426950408889634f);
        float p = __builtin_amdgcn_exp2f(t2);
        if (last && (s*16 + quad*4 + r) > myq) p = 0.f;
        rsum += p;
        pk[r] = f2bf(p);
      }
      *(us4*)&Ps[wave][l16*72 + s*16 + quad*4] = pk;
    }
    l_run += rsum;

    // ---- O^T += V^T · P^T ----
#pragma unroll
    for (int kc = 0; kc < 2; kc++) {
      const bf16x8 pf = *(const bf16x8*)&Ps[wave][l16*72 + kc*32 + quad*8];
#pragma unroll
      for (int dt = 0; dt < 8; dt++) {
        const int d = dt*16 + l16;
        const bf16x8 vf = *(const bf16x8*)&VTs[d*64 + (((kc*4 + quad) ^ (d & 7)))*8];
        Ob[dt] = __builtin_amdgcn_mfma_f32_16x16x32_bf16(vf, pf, Ob[dt], 0, 0, 0);
      }
    }

    if (!last) {
      // readers-done barrier WITHOUT draining the vmem prefetch:
      __builtin_amdgcn_s_waitcnt(0xC07F);   // lgkmcnt(0) only
      __builtin_amdgcn_s_barrier();
      writeKV();                            // vmcnt waits inserted here
      __syncthreads();                      // writes visible (cheap drain)
    }
  }

  l_run += __shfl_xor(l_run, 16);
  l_run += __shfl_xor(l_run, 32);
  const float inv_l = __builtin_amdgcn_rcpf(l_run);
  ushort_t* optr = obuf + (bT + qrow)*2048 + h*128;
#pragma unroll
  for (int dt = 0; dt < 8; dt++) {
    us4 pk;
#pragma unroll
    for (int r = 0; r < 4; r++) pk[r] = f2bf(Ob[dt][r] * inv_l);
    *(us4*)&optr[dt*16 + quad*4] = pk;
  }
}

// ---------------------------------------------------------------------------
// Final GEMM C = A @ B^T with f32-or-bf16 output per flag (unchanged).
// ---------------------------------------------------------------------------
__global__ __launch_bounds__(256) void gemm_final(
    const ushort_t* __restrict__ A, const ushort_t* __restrict__ B,
    ushort_t* __restrict__ C, float* __restrict__ Cf, const int* __restrict__ flag)
{
  __shared__ __align__(16) ushort_t As[128*BK];
  __shared__ __align__(16) ushort_t Bs[128*BK];
  const int tid = threadIdx.x;
  const int lane = tid & 63, wave = tid >> 6;
  const int quad = lane >> 4, l16 = lane & 15;
  const int m0 = blockIdx.y * 128, n0 = blockIdx.x * 128;
  const int wm = (wave >> 1) * 64, wn = (wave & 1) * 64;
  const int srow = lane >> 3, sslot = lane & 7;

  f32x4 acc[4][4];
#pragma unroll
  for (int i = 0; i < 4; i++)
#pragma unroll
    for (int j = 0; j < 4; j++) acc[i][j] = (f32x4){0.f,0.f,0.f,0.f};

  for (int k0 = 0; k0 < 2048; k0 += BK) {
    __syncthreads();
#pragma unroll
    for (int i = 0; i < 4; i++) {
      const int r0 = wave*32 + i*8;
      const int row = r0 + srow;
      const int g = (sslot ^ (row & 7)) * 8;
      async16(A + (size_t)(m0 + row)*2048 + k0 + g, &As[r0*64]);
      async16(B + (size_t)(n0 + row)*2048 + k0 + g, &Bs[r0*64]);
    }
    __syncthreads();
#pragma unroll
    for (int kc = 0; kc < 2; kc++) {
      bf16x8 af[4], bfr[4];
#pragma unroll
      for (int i = 0; i < 4; i++) {
        const int ra = wm + i*16 + l16;
        af[i] = *(const bf16x8*)&As[ra*64 + (((kc*4 + quad) ^ (ra & 7)))*8];
        const int rb = wn + i*16 + l16;
        bfr[i] = *(const bf16x8*)&Bs[rb*64 + (((kc*4 + quad) ^ (rb & 7)))*8];
      }
#pragma unroll
      for (int i = 0; i < 4; i++)
#pragma unroll
        for (int j = 0; j < 4; j++)
          acc[i][j] = __builtin_amdgcn_mfma_f32_16x16x32_bf16(af[i], bfr[j], acc[i][j], 0, 0, 0);
    }
  }
  const bool isf = (*flag != 0);
#pragma unroll
  for (int i = 0; i < 4; i++) {
    const int rbase = m0 + wm + i*16 + quad*4;
#pragma unroll
    for (int j = 0; j < 4; j++) {
      const int col = n0 + wn + j*16 + l16;
#pragma unroll
      for (int r = 0; r < 4; r++) {
        if (isf) Cf[(size_t)(rbase + r)*2048 + col] = acc[i][j][r];
        else     C [(size_t)(rbase + r)*2048 + col] = f2bf(acc[i][j][r]);
      }
    }
  }
}

extern "C" void kernel_launch(void* const* d_in, const int* in_sizes, int n_in,
                              void* d_out, int out_size, void* d_ws, size_t ws_size,
                              hipStream_t stream)
{
  int* flag = (int*)d_ws;
  ushort_t* ws = (ushort_t*)d_ws + 8;
  ushort_t* xb  = ws;                        // 8388608 (aliased as obuf later)
  ushort_t* wqb = xb  + (size_t)8388608;     // 4194304
  ushort_t* wkb = wqb + (size_t)4194304;     // 1048576
  ushort_t* wvb = wkb + (size_t)1048576;     // 1048576
  ushort_t* wob = wvb + (size_t)1048576;     // 4194304
  ushort_t* qgb = wob + (size_t)4194304;     // 128
  ushort_t* kgb = qgb + 128;                 // 128
  ushort_t* qbuf = kgb + 128;                // 8388608
  ushort_t* kbuf  = qbuf + (size_t)8388608;  // 2097152
  ushort_t* vtbuf = kbuf + (size_t)2097152;  // 2097152
  ushort_t* obuf = xb;                       // x dead after qkv_gemm

  detect_f32<<<1, 64, 0, stream>>>((const ushort_t*)d_in[1], flag);
  convert_all<<<18433, 256, 0, stream>>>(
      d_in[0], d_in[1], d_in[2], d_in[3], d_in[4], d_in[5], d_in[6],
      xb, wqb, wkb, wvb, wob, qgb, kgb, flag);

  qkv_gemm<<<dim3(24, 32), 256, 0, stream>>>(xb, wqb, wkb, wvb, qbuf, kbuf, vtbuf);
  rmsnorm_rows<<<dim3(1024), 256, 0, stream>>>(kbuf, kgb);
  attn_fused<<<dim3(32, 16, 2), 256, 0, stream>>>(qbuf, kbuf, vtbuf, qgb, obuf);
  gemm_final<<<dim3(16, 32), 256, 0, stream>>>(obuf, wob, (ushort_t*)d_out, (float*)d_out, flag);
}

// Round 5
// 341.238 us; speedup vs baseline: 1.1466x; 1.1466x over previous
//
#include <hip/hip_runtime.h>

typedef __attribute__((ext_vector_type(4))) float f32x4;
typedef __attribute__((ext_vector_type(8))) short bf16x8;
typedef __attribute__((ext_vector_type(4))) unsigned short us4;
typedef unsigned short ushort_t;

__device__ __forceinline__ float bf2f(ushort_t u){
  union { unsigned int i; float f; } v; v.i = ((unsigned int)u) << 16; return v.f;
}
__device__ __forceinline__ ushort_t f2bf(float f){
  union { float f; unsigned int i; } v; v.f = f;
  unsigned int r = v.i + 0x7fffu + ((v.i >> 16) & 1u);
  return (ushort_t)(r >> 16);
}
__device__ __forceinline__ void async16(const ushort_t* g, ushort_t* l){
  __builtin_amdgcn_global_load_lds(
      (const __attribute__((address_space(1))) unsigned int*)g,
      (__attribute__((address_space(3))) unsigned int*)l, 16, 0, 0);
}

// ---------------------------------------------------------------------------
// Dtype detection (f32 vs bf16 inputs) — validated.
// ---------------------------------------------------------------------------
__global__ void detect_f32(const ushort_t* __restrict__ probe, int* __restrict__ flag){
  const int lane = threadIdx.x;
  int big = 0;
  for (int i = lane; i < 4096; i += 64) {
    const int ex = (probe[i] >> 7) & 0xFF;
    if (ex >= 0x90) big++;
  }
#pragma unroll
  for (int off = 32; off > 0; off >>= 1) big += __shfl_xor(big, off);
  if (lane == 0) *flag = (big > 16) ? 1 : 0;
}

// ---------------------------------------------------------------------------
// One fused convert for all 7 inputs.
// ---------------------------------------------------------------------------
__global__ __launch_bounds__(256) void convert_all(
    const void* s0, const void* s1, const void* s2, const void* s3,
    const void* s4, const void* s5, const void* s6,
    ushort_t* d0, ushort_t* d1, ushort_t* d2, ushort_t* d3,
    ushort_t* d4, ushort_t* d5, ushort_t* d6,
    const int* __restrict__ flag)
{
  long i = ((long)blockIdx.x * 256 + threadIdx.x) * 4;
  if (i >= 18874624L) return;
  const void* src; ushort_t* dst; long loc;
  if      (i <  8388608L) { src = s0; dst = d0; loc = i; }
  else if (i < 12582912L) { src = s1; dst = d1; loc = i - 8388608L; }
  else if (i < 13631488L) { src = s2; dst = d2; loc = i - 12582912L; }
  else if (i < 14680064L) { src = s3; dst = d3; loc = i - 13631488L; }
  else if (i < 18874368L) { src = s4; dst = d4; loc = i - 14680064L; }
  else if (i < 18874496L) { src = s5; dst = d5; loc = i - 18874368L; }
  else                    { src = s6; dst = d6; loc = i - 18874496L; }
  if (*flag != 0) {
    f32x4 v = *(const f32x4*)((const float*)src + loc);
    us4 o; o[0] = f2bf(v[0]); o[1] = f2bf(v[1]); o[2] = f2bf(v[2]); o[3] = f2bf(v[3]);
    *(us4*)(dst + loc) = o;
  } else {
    *(us4*)(dst + loc) = *(const us4*)((const ushort_t*)src + loc);
  }
}

// ---------------------------------------------------------------------------
// Fused QKV GEMM (unchanged; V region writes V^T layout).
// ---------------------------------------------------------------------------
#define BK 64
__global__ __launch_bounds__(256) void qkv_gemm(
    const ushort_t* __restrict__ A,
    const ushort_t* __restrict__ Wq, const ushort_t* __restrict__ Wk,
    const ushort_t* __restrict__ Wv,
    ushort_t* __restrict__ Q, ushort_t* __restrict__ Kb, ushort_t* __restrict__ Vt)
{
  __shared__ __align__(16) ushort_t As[128*BK];
  __shared__ __align__(16) ushort_t Bs[128*BK];
  const int tid = threadIdx.x;
  const int lane = tid & 63, wave = tid >> 6;
  const int quad = lane >> 4, l16 = lane & 15;
  const int m0 = blockIdx.y * 128;
  const int n0g = blockIdx.x * 128;
  const ushort_t* B; int n0, mode;
  if      (n0g < 2048) { B = Wq; n0 = n0g;        mode = 0; }
  else if (n0g < 2560) { B = Wk; n0 = n0g - 2048; mode = 1; }
  else                 { B = Wv; n0 = n0g - 2560; mode = 2; }
  const int wm = (wave >> 1) * 64, wn = (wave & 1) * 64;
  const int srow = lane >> 3, sslot = lane & 7;

  f32x4 acc[4][4];
#pragma unroll
  for (int i = 0; i < 4; i++)
#pragma unroll
    for (int j = 0; j < 4; j++) acc[i][j] = (f32x4){0.f,0.f,0.f,0.f};

  for (int k0 = 0; k0 < 2048; k0 += BK) {
    __syncthreads();
#pragma unroll
    for (int i = 0; i < 4; i++) {
      const int r0 = wave*32 + i*8;
      const int row = r0 + srow;
      const int g = (sslot ^ (row & 7)) * 8;
      async16(A + (size_t)(m0 + row)*2048 + k0 + g, &As[r0*64]);
      async16(B + (size_t)(n0 + row)*2048 + k0 + g, &Bs[r0*64]);
    }
    __syncthreads();
#pragma unroll
    for (int kc = 0; kc < 2; kc++) {
      bf16x8 af[4], bfr[4];
#pragma unroll
      for (int i = 0; i < 4; i++) {
        const int ra = wm + i*16 + l16;
        af[i] = *(const bf16x8*)&As[ra*64 + (((kc*4 + quad) ^ (ra & 7)))*8];
        const int rb = wn + i*16 + l16;
        bfr[i] = *(const bf16x8*)&Bs[rb*64 + (((kc*4 + quad) ^ (rb & 7)))*8];
      }
#pragma unroll
      for (int i = 0; i < 4; i++)
#pragma unroll
        for (int j = 0; j < 4; j++)
          acc[i][j] = __builtin_amdgcn_mfma_f32_16x16x32_bf16(af[i], bfr[j], acc[i][j], 0, 0, 0);
    }
  }
#pragma unroll
  for (int i = 0; i < 4; i++) {
    const int rbase = m0 + wm + i*16 + quad*4;
#pragma unroll
    for (int j = 0; j < 4; j++) {
      const int col = n0 + wn + j*16 + l16;
      if (mode == 0) {
#pragma unroll
        for (int r = 0; r < 4; r++) Q[(size_t)(rbase + r)*2048 + col] = f2bf(acc[i][j][r]);
      } else if (mode == 1) {
#pragma unroll
        for (int r = 0; r < 4; r++) Kb[(size_t)(rbase + r)*512 + col] = f2bf(acc[i][j][r]);
      } else {
        us4 pk;
#pragma unroll
        for (int r = 0; r < 4; r++) pk[r] = f2bf(acc[i][j][r]);
        const size_t addr = (size_t)((rbase >> 11)*512 + col)*2048 + (rbase & 2047);
        *(us4*)&Vt[addr] = pk;
      }
    }
  }
}

// ---------------------------------------------------------------------------
// Per-128-dim RMSNorm in place (K). bf16x8 per lane: 4 rows/wave.
// ---------------------------------------------------------------------------
__global__ __launch_bounds__(256) void rmsnorm_rows(
    ushort_t* __restrict__ buf, const ushort_t* __restrict__ gamma)
{
  const int lane = threadIdx.x & 63, wave = threadIdx.x >> 6;
  const int quad = lane >> 4, l16 = lane & 15;
  const int vec = blockIdx.x*16 + wave*4 + quad;
  const size_t base = (size_t)vec*128 + l16*8;
  bf16x8 v = *(const bf16x8*)&buf[base];
  float f[8]; float ss = 0.f;
#pragma unroll
  for (int j = 0; j < 8; j++) { f[j] = bf2f((ushort_t)v[j]); ss += f[j]*f[j]; }
#pragma unroll
  for (int off = 1; off < 16; off <<= 1) ss += __shfl_xor(ss, off);
  const float sc = rsqrtf(ss * (1.0f/128.0f) + 1e-6f);
  bf16x8 g = *(const bf16x8*)&gamma[l16*8];
  bf16x8 o;
#pragma unroll
  for (int j = 0; j < 8; j++) o[j] = (short)f2bf(f[j]*sc*bf2f((ushort_t)g[j]));
  *(bf16x8*)&buf[base] = o;
}

// ---------------------------------------------------------------------------
// Flash attention. Q-tile 128 rows/block (32/wave as 2 groups of 16): each
// K/V LDS fragment read feeds TWO MFMAs, halving DS-pipe bytes per FLOP (the
// round-4 bottleneck: ~48us of ds_read issue). Single-buffer LDS + register
// prefetch + lgkm-only barrier. Softmax: fused softcap-exp (1 transcendental),
// truncating bf16 pack (raw shift/merge), diag-mask specialized via uniform
// branch so non-diag tiles pay zero mask VALU. Causal tail tile (group1-only)
// is a separate block after the main loop.
// ---------------------------------------------------------------------------
__global__ __launch_bounds__(256, 2) void attn_fused(
    const ushort_t* __restrict__ qbuf, const ushort_t* __restrict__ kbuf,
    const ushort_t* __restrict__ vtbuf, const ushort_t* __restrict__ qgamma,
    ushort_t* __restrict__ obuf)
{
  __shared__ __align__(16) ushort_t Ks[64*128];     // [key][dim], swizzled
  __shared__ __align__(16) ushort_t VTs[128*64];    // [dim][key], swizzled
  __shared__ __align__(16) ushort_t Ps[4][2][16*72];// [wave][grp][q][64+pad]
  const int tid = threadIdx.x;
  const int lane = tid & 63, wave = tid >> 6;
  const int quad = lane >> 4, l16 = lane & 15;
  const int bx = 15 - blockIdx.x;          // longest blocks dispatch first
  const int h = blockIdx.y, b = blockIdx.z;
  const int kvh = h >> 2;
  const size_t bT = (size_t)b * 2048;
  const int qrow0 = bx*128 + wave*16 + l16;
  const int qrow1 = qrow0 + 64;
  const size_t vbase = ((size_t)(b*4 + kvh)) * 128 * 2048;
  const int myq = wave*16 + l16;

  // ---- Q load + fused RMSNorm for both groups ----
  bf16x8 qf0[4], qf1[4];
  {
    const ushort_t* qp0 = qbuf + (bT + qrow0)*2048 + h*128;
    const ushort_t* qp1 = qbuf + (bT + qrow1)*2048 + h*128;
    float qv0[4][8], qv1[4][8];
    float ss0 = 0.f, ss1 = 0.f;
#pragma unroll
    for (int kc = 0; kc < 4; kc++) {
      bf16x8 v0 = *(const bf16x8*)&qp0[kc*32 + quad*8];
      bf16x8 v1 = *(const bf16x8*)&qp1[kc*32 + quad*8];
#pragma unroll
      for (int j = 0; j < 8; j++) {
        float f0 = bf2f((ushort_t)v0[j]); qv0[kc][j] = f0; ss0 += f0*f0;
        float f1 = bf2f((ushort_t)v1[j]); qv1[kc][j] = f1; ss1 += f1*f1;
      }
    }
    ss0 += __shfl_xor(ss0, 16); ss0 += __shfl_xor(ss0, 32);
    ss1 += __shfl_xor(ss1, 16); ss1 += __shfl_xor(ss1, 32);
    const float sc0 = rsqrtf(ss0*(1.0f/128.0f) + 1e-6f) * 0.08838834764831845f;
    const float sc1 = rsqrtf(ss1*(1.0f/128.0f) + 1e-6f) * 0.08838834764831845f;
#pragma unroll
    for (int kc = 0; kc < 4; kc++) {
      bf16x8 g = *(const bf16x8*)&qgamma[kc*32 + quad*8];
      bf16x8 o0, o1;
#pragma unroll
      for (int j = 0; j < 8; j++) {
        const float gg = bf2f((ushort_t)g[j]);
        o0[j] = (short)f2bf(qv0[kc][j] * sc0 * gg);
        o1[j] = (short)f2bf(qv1[kc][j] * sc1 * gg);
      }
      qf0[kc] = o0; qf1[kc] = o1;
    }
  }

  f32x4 Ob0[8], Ob1[8];
#pragma unroll
  for (int i = 0; i < 8; i++) { Ob0[i] = (f32x4){0.f,0.f,0.f,0.f}; Ob1[i] = (f32x4){0.f,0.f,0.f,0.f}; }
  float l0 = 0.f, l1 = 0.f;

  ushort_t* ps0 = &Ps[wave][0][l16*72];
  ushort_t* ps1 = &Ps[wave][1][l16*72];

  // ---- staging: global->reg prefetch, reg->LDS (round-3 swizzle layout) ----
  const ushort_t* kg0 = kbuf + (bT + wave*16 + (lane>>4))*512 + kvh*128;
  const ushort_t* vg0 = vtbuf + vbase + (size_t)(wave*32 + (lane>>3))*2048;
  bf16x8 kreg[4], vreg[4];
  auto loadKV = [&](int kb){
#pragma unroll
    for (int i = 0; i < 4; i++) {
      const int sw = ((lane & 15) ^ ((i*4 + (lane>>4)) & 15)) * 8;
      kreg[i] = *(const bf16x8*)(kg0 + (size_t)(kb*64 + i*4)*512 + sw);
    }
#pragma unroll
    for (int i = 0; i < 4; i++) {
      const int sw = ((lane & 7) ^ ((i*8 + (lane>>3)) & 7)) * 8;
      vreg[i] = *(const bf16x8*)(vg0 + (size_t)(i*8)*2048 + kb*64 + sw);
    }
  };
  auto writeKV = [&](){
#pragma unroll
    for (int i = 0; i < 4; i++)
      *(bf16x8*)&Ks[(wave*16 + i*4)*128 + lane*8] = kreg[i];
#pragma unroll
    for (int i = 0; i < 4; i++)
      *(bf16x8*)&VTs[(wave*32 + i*8)*64 + lane*8] = vreg[i];
  };

  // softcap+softmax: p = exp2(x*(c0+c1*w+c2*w^2)), w=x^2; truncating bf16 pack
  auto sm = [&](f32x4* st, ushort_t* psb, bool diag) -> float {
    float rsum = 0.f;
#pragma unroll
    for (int s = 0; s < 4; s++) {
      float p[4];
#pragma unroll
      for (int r = 0; r < 4; r++) {
        const float x = st[s][r];
        const float w = x*x;
        const float t2 = x * __builtin_fmaf(w,
            __builtin_fmaf(w, 3.0777494e-8f, -1.9235934e-4f), 1.4426950408889634f);
        float pp = __builtin_amdgcn_exp2f(t2);
        if (diag && (s*16 + quad*4 + r) > myq) pp = 0.f;
        rsum += pp;
        p[r] = pp;
      }
      uint2 pk;
      pk.x = (__float_as_uint(p[0]) >> 16) | (__float_as_uint(p[1]) & 0xFFFF0000u);
      pk.y = (__float_as_uint(p[2]) >> 16) | (__float_as_uint(p[3]) & 0xFFFF0000u);
      *(uint2*)&psb[s*16 + quad*4] = pk;
    }
    return rsum;
  };

  loadKV(0);
  writeKV();
  __syncthreads();

  // ---- main loop: tiles 0..2bx (both groups); tile 2bx is group0's diag ----
  const int ndiag = 2*bx;
  for (int kb = 0; kb <= ndiag; kb++) {
    loadKV(kb+1);                     // tail tile always follows

    // S^T = K · Q^T for both groups, kf loaded once
    f32x4 st0[4], st1[4];
#pragma unroll
    for (int s = 0; s < 4; s++) { st0[s] = (f32x4){0.f,0.f,0.f,0.f}; st1[s] = (f32x4){0.f,0.f,0.f,0.f}; }
#pragma unroll
    for (int s = 0; s < 4; s++) {
      const int row = s*16 + l16;
#pragma unroll
      for (int kc = 0; kc < 4; kc++) {
        const bf16x8 kf = *(const bf16x8*)&Ks[row*128 + (((kc*4 + quad) ^ (row & 15)))*8];
        st0[s] = __builtin_amdgcn_mfma_f32_16x16x32_bf16(kf, qf0[kc], st0[s], 0, 0, 0);
        st1[s] = __builtin_amdgcn_mfma_f32_16x16x32_bf16(kf, qf1[kc], st1[s], 0, 0, 0);
      }
    }

    if (kb == ndiag) l0 += sm(st0, ps0, true);
    else             l0 += sm(st0, ps0, false);
    l1 += sm(st1, ps1, false);

    // O^T += V^T · P^T, vf loaded once per both groups
#pragma unroll
    for (int kc = 0; kc < 2; kc++) {
      const bf16x8 pf0 = *(const bf16x8*)&ps0[kc*32 + quad*8];
      const bf16x8 pf1 = *(const bf16x8*)&ps1[kc*32 + quad*8];
#pragma unroll
      for (int dt = 0; dt < 8; dt++) {
        const int d = dt*16 + l16;
        const bf16x8 vf = *(const bf16x8*)&VTs[d*64 + (((kc*4 + quad) ^ (d & 7)))*8];
        Ob0[dt] = __builtin_amdgcn_mfma_f32_16x16x32_bf16(vf, pf0, Ob0[dt], 0, 0, 0);
        Ob1[dt] = __builtin_amdgcn_mfma_f32_16x16x32_bf16(vf, pf1, Ob1[dt], 0, 0, 0);
      }
    }

    // readers-done barrier WITHOUT draining the vmem prefetch
    __builtin_amdgcn_s_waitcnt(0xC07F);   // lgkmcnt(0) only
    __builtin_amdgcn_s_barrier();
    writeKV();
    __syncthreads();
  }

  // ---- tail tile (kb = 2bx+1): group1 only, its diagonal ----
  {
    f32x4 st1[4];
#pragma unroll
    for (int s = 0; s < 4; s++) st1[s] = (f32x4){0.f,0.f,0.f,0.f};
#pragma unroll
    for (int s = 0; s < 4; s++) {
      const int row = s*16 + l16;
#pragma unroll
      for (int kc = 0; kc < 4; kc++) {
        const bf16x8 kf = *(const bf16x8*)&Ks[row*128 + (((kc*4 + quad) ^ (row & 15)))*8];
        st1[s] = __builtin_amdgcn_mfma_f32_16x16x32_bf16(kf, qf1[kc], st1[s], 0, 0, 0);
      }
    }
    l1 += sm(st1, ps1, true);
#pragma unroll
    for (int kc = 0; kc < 2; kc++) {
      const bf16x8 pf1 = *(const bf16x8*)&ps1[kc*32 + quad*8];
#pragma unroll
      for (int dt = 0; dt < 8; dt++) {
        const int d = dt*16 + l16;
        const bf16x8 vf = *(const bf16x8*)&VTs[d*64 + (((kc*4 + quad) ^ (d & 7)))*8];
        Ob1[dt] = __builtin_amdgcn_mfma_f32_16x16x32_bf16(vf, pf1, Ob1[dt], 0, 0, 0);
      }
    }
  }

  l0 += __shfl_xor(l0, 16); l0 += __shfl_xor(l0, 32);
  l1 += __shfl_xor(l1, 16); l1 += __shfl_xor(l1, 32);
  const float inv0 = __builtin_amdgcn_rcpf(l0);
  const float inv1 = __builtin_amdgcn_rcpf(l1);
  ushort_t* op0 = obuf + (bT + qrow0)*2048 + h*128;
  ushort_t* op1 = obuf + (bT + qrow1)*2048 + h*128;
#pragma unroll
  for (int dt = 0; dt < 8; dt++) {
    us4 pk0, pk1;
#pragma unroll
    for (int r = 0; r < 4; r++) {
      pk0[r] = f2bf(Ob0[dt][r] * inv0);
      pk1[r] = f2bf(Ob1[dt][r] * inv1);
    }
    *(us4*)&op0[dt*16 + quad*4] = pk0;
    *(us4*)&op1[dt*16 + quad*4] = pk1;
  }
}

// ---------------------------------------------------------------------------
// Final GEMM C = A @ B^T with f32-or-bf16 output per flag (unchanged).
// ---------------------------------------------------------------------------
__global__ __launch_bounds__(256) void gemm_final(
    const ushort_t* __restrict__ A, const ushort_t* __restrict__ B,
    ushort_t* __restrict__ C, float* __restrict__ Cf, const int* __restrict__ flag)
{
  __shared__ __align__(16) ushort_t As[128*BK];
  __shared__ __align__(16) ushort_t Bs[128*BK];
  const int tid = threadIdx.x;
  const int lane = tid & 63, wave = tid >> 6;
  const int quad = lane >> 4, l16 = lane & 15;
  const int m0 = blockIdx.y * 128, n0 = blockIdx.x * 128;
  const int wm = (wave >> 1) * 64, wn = (wave & 1) * 64;
  const int srow = lane >> 3, sslot = lane & 7;

  f32x4 acc[4][4];
#pragma unroll
  for (int i = 0; i < 4; i++)
#pragma unroll
    for (int j = 0; j < 4; j++) acc[i][j] = (f32x4){0.f,0.f,0.f,0.f};

  for (int k0 = 0; k0 < 2048; k0 += BK) {
    __syncthreads();
#pragma unroll
    for (int i = 0; i < 4; i++) {
      const int r0 = wave*32 + i*8;
      const int row = r0 + srow;
      const int g = (sslot ^ (row & 7)) * 8;
      async16(A + (size_t)(m0 + row)*2048 + k0 + g, &As[r0*64]);
      async16(B + (size_t)(n0 + row)*2048 + k0 + g, &Bs[r0*64]);
    }
    __syncthreads();
#pragma unroll
    for (int kc = 0; kc < 2; kc++) {
      bf16x8 af[4], bfr[4];
#pragma unroll
      for (int i = 0; i < 4; i++) {
        const int ra = wm + i*16 + l16;
        af[i] = *(const bf16x8*)&As[ra*64 + (((kc*4 + quad) ^ (ra & 7)))*8];
        const int rb = wn + i*16 + l16;
        bfr[i] = *(const bf16x8*)&Bs[rb*64 + (((kc*4 + quad) ^ (rb & 7)))*8];
      }
#pragma unroll
      for (int i = 0; i < 4; i++)
#pragma unroll
        for (int j = 0; j < 4; j++)
          acc[i][j] = __builtin_amdgcn_mfma_f32_16x16x32_bf16(af[i], bfr[j], acc[i][j], 0, 0, 0);
    }
  }
  const bool isf = (*flag != 0);
#pragma unroll
  for (int i = 0; i < 4; i++) {
    const int rbase = m0 + wm + i*16 + quad*4;
#pragma unroll
    for (int j = 0; j < 4; j++) {
      const int col = n0 + wn + j*16 + l16;
#pragma unroll
      for (int r = 0; r < 4; r++) {
        if (isf) Cf[(size_t)(rbase + r)*2048 + col] = acc[i][j][r];
        else     C [(size_t)(rbase + r)*2048 + col] = f2bf(acc[i][j][r]);
      }
    }
  }
}

extern "C" void kernel_launch(void* const* d_in, const int* in_sizes, int n_in,
                              void* d_out, int out_size, void* d_ws, size_t ws_size,
                              hipStream_t stream)
{
  int* flag = (int*)d_ws;
  ushort_t* ws = (ushort_t*)d_ws + 8;
  ushort_t* xb  = ws;                        // 8388608 (aliased as obuf later)
  ushort_t* wqb = xb  + (size_t)8388608;     // 4194304
  ushort_t* wkb = wqb + (size_t)4194304;     // 1048576
  ushort_t* wvb = wkb + (size_t)1048576;     // 1048576
  ushort_t* wob = wvb + (size_t)1048576;     // 4194304
  ushort_t* qgb = wob + (size_t)4194304;     // 128
  ushort_t* kgb = qgb + 128;                 // 128
  ushort_t* qbuf = kgb + 128;                // 8388608
  ushort_t* kbuf  = qbuf + (size_t)8388608;  // 2097152
  ushort_t* vtbuf = kbuf + (size_t)2097152;  // 2097152
  ushort_t* obuf = xb;                       // x dead after qkv_gemm

  detect_f32<<<1, 64, 0, stream>>>((const ushort_t*)d_in[1], flag);
  convert_all<<<18433, 256, 0, stream>>>(
      d_in[0], d_in[1], d_in[2], d_in[3], d_in[4], d_in[5], d_in[6],
      xb, wqb, wkb, wvb, wob, qgb, kgb, flag);

  qkv_gemm<<<dim3(24, 32), 256, 0, stream>>>(xb, wqb, wkb, wvb, qbuf, kbuf, vtbuf);
  rmsnorm_rows<<<dim3(1024), 256, 0, stream>>>(kbuf, kgb);
  attn_fused<<<dim3(16, 16, 2), 256, 0, stream>>>(qbuf, kbuf, vtbuf, qgb, obuf);
  gemm_final<<<dim3(16, 32), 256, 0, stream>>>(obuf, wob, (ushort_t*)d_out, (float*)d_out, flag);
}

// Round 6
// 325.521 us; speedup vs baseline: 1.2020x; 1.0483x over previous
//
#include <hip/hip_runtime.h>

typedef __attribute__((ext_vector_type(4))) float f32x4;
typedef __attribute__((ext_vector_type(8))) short bf16x8;
typedef __attribute__((ext_vector_type(4))) unsigned short us4;
typedef unsigned short ushort_t;

__device__ __forceinline__ float bf2f(ushort_t u){
  union { unsigned int i; float f; } v; v.i = ((unsigned int)u) << 16; return v.f;
}
__device__ __forceinline__ ushort_t f2bf(float f){
  union { float f; unsigned int i; } v; v.f = f;
  unsigned int r = v.i + 0x7fffu + ((v.i >> 16) & 1u);
  return (ushort_t)(r >> 16);
}
__device__ __forceinline__ void async16(const ushort_t* g, ushort_t* l){
  __builtin_amdgcn_global_load_lds(
      (const __attribute__((address_space(1))) unsigned int*)g,
      (__attribute__((address_space(3))) unsigned int*)l, 16, 0, 0);
}

// ---------------------------------------------------------------------------
// Dtype detection (f32 vs bf16 inputs) — validated.
// ---------------------------------------------------------------------------
__global__ void detect_f32(const ushort_t* __restrict__ probe, int* __restrict__ flag){
  const int lane = threadIdx.x;
  int big = 0;
  for (int i = lane; i < 4096; i += 64) {
    const int ex = (probe[i] >> 7) & 0xFF;
    if (ex >= 0x90) big++;
  }
#pragma unroll
  for (int off = 32; off > 0; off >>= 1) big += __shfl_xor(big, off);
  if (lane == 0) *flag = (big > 16) ? 1 : 0;
}

// ---------------------------------------------------------------------------
// One fused convert for all 7 inputs.
// ---------------------------------------------------------------------------
__global__ __launch_bounds__(256) void convert_all(
    const void* s0, const void* s1, const void* s2, const void* s3,
    const void* s4, const void* s5, const void* s6,
    ushort_t* d0, ushort_t* d1, ushort_t* d2, ushort_t* d3,
    ushort_t* d4, ushort_t* d5, ushort_t* d6,
    const int* __restrict__ flag)
{
  long i = ((long)blockIdx.x * 256 + threadIdx.x) * 4;
  if (i >= 18874624L) return;
  const void* src; ushort_t* dst; long loc;
  if      (i <  8388608L) { src = s0; dst = d0; loc = i; }
  else if (i < 12582912L) { src = s1; dst = d1; loc = i - 8388608L; }
  else if (i < 13631488L) { src = s2; dst = d2; loc = i - 12582912L; }
  else if (i < 14680064L) { src = s3; dst = d3; loc = i - 13631488L; }
  else if (i < 18874368L) { src = s4; dst = d4; loc = i - 14680064L; }
  else if (i < 18874496L) { src = s5; dst = d5; loc = i - 18874368L; }
  else                    { src = s6; dst = d6; loc = i - 18874496L; }
  if (*flag != 0) {
    f32x4 v = *(const f32x4*)((const float*)src + loc);
    us4 o; o[0] = f2bf(v[0]); o[1] = f2bf(v[1]); o[2] = f2bf(v[2]); o[3] = f2bf(v[3]);
    *(us4*)(dst + loc) = o;
  } else {
    *(us4*)(dst + loc) = *(const us4*)((const ushort_t*)src + loc);
  }
}

// ---------------------------------------------------------------------------
// Fused QKV GEMM (unchanged; V region writes V^T layout).
// ---------------------------------------------------------------------------
#define BK 64
__global__ __launch_bounds__(256) void qkv_gemm(
    const ushort_t* __restrict__ A,
    const ushort_t* __restrict__ Wq, const ushort_t* __restrict__ Wk,
    const ushort_t* __restrict__ Wv,
    ushort_t* __restrict__ Q, ushort_t* __restrict__ Kb, ushort_t* __restrict__ Vt)
{
  __shared__ __align__(16) ushort_t As[128*BK];
  __shared__ __align__(16) ushort_t Bs[128*BK];
  const int tid = threadIdx.x;
  const int lane = tid & 63, wave = tid >> 6;
  const int quad = lane >> 4, l16 = lane & 15;
  const int m0 = blockIdx.y * 128;
  const int n0g = blockIdx.x * 128;
  const ushort_t* B; int n0, mode;
  if      (n0g < 2048) { B = Wq; n0 = n0g;        mode = 0; }
  else if (n0g < 2560) { B = Wk; n0 = n0g - 2048; mode = 1; }
  else                 { B = Wv; n0 = n0g - 2560; mode = 2; }
  const int wm = (wave >> 1) * 64, wn = (wave & 1) * 64;
  const int srow = lane >> 3, sslot = lane & 7;

  f32x4 acc[4][4];
#pragma unroll
  for (int i = 0; i < 4; i++)
#pragma unroll
    for (int j = 0; j < 4; j++) acc[i][j] = (f32x4){0.f,0.f,0.f,0.f};

  for (int k0 = 0; k0 < 2048; k0 += BK) {
    __syncthreads();
#pragma unroll
    for (int i = 0; i < 4; i++) {
      const int r0 = wave*32 + i*8;
      const int row = r0 + srow;
      const int g = (sslot ^ (row & 7)) * 8;
      async16(A + (size_t)(m0 + row)*2048 + k0 + g, &As[r0*64]);
      async16(B + (size_t)(n0 + row)*2048 + k0 + g, &Bs[r0*64]);
    }
    __syncthreads();
#pragma unroll
    for (int kc = 0; kc < 2; kc++) {
      bf16x8 af[4], bfr[4];
#pragma unroll
      for (int i = 0; i < 4; i++) {
        const int ra = wm + i*16 + l16;
        af[i] = *(const bf16x8*)&As[ra*64 + (((kc*4 + quad) ^ (ra & 7)))*8];
        const int rb = wn + i*16 + l16;
        bfr[i] = *(const bf16x8*)&Bs[rb*64 + (((kc*4 + quad) ^ (rb & 7)))*8];
      }
#pragma unroll
      for (int i = 0; i < 4; i++)
#pragma unroll
        for (int j = 0; j < 4; j++)
          acc[i][j] = __builtin_amdgcn_mfma_f32_16x16x32_bf16(af[i], bfr[j], acc[i][j], 0, 0, 0);
    }
  }
#pragma unroll
  for (int i = 0; i < 4; i++) {
    const int rbase = m0 + wm + i*16 + quad*4;
#pragma unroll
    for (int j = 0; j < 4; j++) {
      const int col = n0 + wn + j*16 + l16;
      if (mode == 0) {
#pragma unroll
        for (int r = 0; r < 4; r++) Q[(size_t)(rbase + r)*2048 + col] = f2bf(acc[i][j][r]);
      } else if (mode == 1) {
#pragma unroll
        for (int r = 0; r < 4; r++) Kb[(size_t)(rbase + r)*512 + col] = f2bf(acc[i][j][r]);
      } else {
        us4 pk;
#pragma unroll
        for (int r = 0; r < 4; r++) pk[r] = f2bf(acc[i][j][r]);
        const size_t addr = (size_t)((rbase >> 11)*512 + col)*2048 + (rbase & 2047);
        *(us4*)&Vt[addr] = pk;
      }
    }
  }
}

// ---------------------------------------------------------------------------
// Per-128-dim RMSNorm in place (K). bf16x8 per lane: 4 rows/wave.
// ---------------------------------------------------------------------------
__global__ __launch_bounds__(256) void rmsnorm_rows(
    ushort_t* __restrict__ buf, const ushort_t* __restrict__ gamma)
{
  const int lane = threadIdx.x & 63, wave = threadIdx.x >> 6;
  const int quad = lane >> 4, l16 = lane & 15;
  const int vec = blockIdx.x*16 + wave*4 + quad;
  const size_t base = (size_t)vec*128 + l16*8;
  bf16x8 v = *(const bf16x8*)&buf[base];
  float f[8]; float ss = 0.f;
#pragma unroll
  for (int j = 0; j < 8; j++) { f[j] = bf2f((ushort_t)v[j]); ss += f[j]*f[j]; }
#pragma unroll
  for (int off = 1; off < 16; off <<= 1) ss += __shfl_xor(ss, off);
  const float sc = rsqrtf(ss * (1.0f/128.0f) + 1e-6f);
  bf16x8 g = *(const bf16x8*)&gamma[l16*8];
  bf16x8 o;
#pragma unroll
  for (int j = 0; j < 8; j++) o[j] = (short)f2bf(f[j]*sc*bf2f((ushort_t)g[j]));
  *(bf16x8*)&buf[base] = o;
}

// ---------------------------------------------------------------------------
// Flash attention. CAUSAL-PAIRED: each block runs two sequential phases with
// Q-tiles bx=p and bx=15-p, so every block does exactly 34 K-tiles — perfect
// static load balance at grid 256 = 1 block/CU (round-5 imbalance: Occ 11%).
// Per-phase structure = round 5: Q-tile 128 (2 groups/wave, K/V LDS reads
// amortized over both), single-buffer LDS + register prefetch + lgkm-only
// barrier, 1-transcendental softcap-softmax, truncating bf16 P-pack.
// ---------------------------------------------------------------------------
__global__ __launch_bounds__(256, 1) void attn_fused(
    const ushort_t* __restrict__ qbuf, const ushort_t* __restrict__ kbuf,
    const ushort_t* __restrict__ vtbuf, const ushort_t* __restrict__ qgamma,
    ushort_t* __restrict__ obuf)
{
  __shared__ __align__(16) ushort_t Ks[64*128];     // [key][dim], swizzled
  __shared__ __align__(16) ushort_t VTs[128*64];    // [dim][key], swizzled
  __shared__ __align__(16) ushort_t Ps[4][2][16*72];// [wave][grp][q][64+pad]
  const int tid = threadIdx.x;
  const int lane = tid & 63, wave = tid >> 6;
  const int quad = lane >> 4, l16 = lane & 15;
  const int p = blockIdx.x;                // pair index 0..7
  const int h = blockIdx.y, b = blockIdx.z;
  const int kvh = h >> 2;
  const size_t bT = (size_t)b * 2048;
  const size_t vbase = ((size_t)(b*4 + kvh)) * 128 * 2048;
  const int myq = wave*16 + l16;

  ushort_t* ps0 = &Ps[wave][0][l16*72];
  ushort_t* ps1 = &Ps[wave][1][l16*72];

  // staging pointers (phase-independent)
  const ushort_t* kg0 = kbuf + (bT + wave*16 + (lane>>4))*512 + kvh*128;
  const ushort_t* vg0 = vtbuf + vbase + (size_t)(wave*32 + (lane>>3))*2048;
  bf16x8 kreg[4], vreg[4];
  auto loadKV = [&](int kb){
#pragma unroll
    for (int i = 0; i < 4; i++) {
      const int sw = ((lane & 15) ^ ((i*4 + (lane>>4)) & 15)) * 8;
      kreg[i] = *(const bf16x8*)(kg0 + (size_t)(kb*64 + i*4)*512 + sw);
    }
#pragma unroll
    for (int i = 0; i < 4; i++) {
      const int sw = ((lane & 7) ^ ((i*8 + (lane>>3)) & 7)) * 8;
      vreg[i] = *(const bf16x8*)(vg0 + (size_t)(i*8)*2048 + kb*64 + sw);
    }
  };
  auto writeKV = [&](){
#pragma unroll
    for (int i = 0; i < 4; i++)
      *(bf16x8*)&Ks[(wave*16 + i*4)*128 + lane*8] = kreg[i];
#pragma unroll
    for (int i = 0; i < 4; i++)
      *(bf16x8*)&VTs[(wave*32 + i*8)*64 + lane*8] = vreg[i];
  };

  // softcap+softmax: p = exp2(x*(c0+c1*w+c2*w^2)), w=x^2; truncating bf16 pack
  auto sm = [&](f32x4* st, ushort_t* psb, bool diag) -> float {
    float rsum = 0.f;
#pragma unroll
    for (int s = 0; s < 4; s++) {
      float pv[4];
#pragma unroll
      for (int r = 0; r < 4; r++) {
        const float x = st[s][r];
        const float w = x*x;
        const float t2 = x * __builtin_fmaf(w,
            __builtin_fmaf(w, 3.0777494e-8f, -1.9235934e-4f), 1.4426950408889634f);
        float pp = __builtin_amdgcn_exp2f(t2);
        if (diag && (s*16 + quad*4 + r) > myq) pp = 0.f;
        rsum += pp;
        pv[r] = pp;
      }
      uint2 pk;
      pk.x = (__float_as_uint(pv[0]) >> 16) | (__float_as_uint(pv[1]) & 0xFFFF0000u);
      pk.y = (__float_as_uint(pv[2]) >> 16) | (__float_as_uint(pv[3]) & 0xFFFF0000u);
      *(uint2*)&psb[s*16 + quad*4] = pk;
    }
    return rsum;
  };

  for (int ph = 0; ph < 2; ph++) {
    const int bx = ph ? (15 - p) : p;
    const int qrow0 = bx*128 + wave*16 + l16;
    const int qrow1 = qrow0 + 64;

    // ---- Q load + fused RMSNorm for both groups ----
    bf16x8 qf0[4], qf1[4];
    {
      const ushort_t* qp0 = qbuf + (bT + qrow0)*2048 + h*128;
      const ushort_t* qp1 = qbuf + (bT + qrow1)*2048 + h*128;
      float qv0[4][8], qv1[4][8];
      float ss0 = 0.f, ss1 = 0.f;
#pragma unroll
      for (int kc = 0; kc < 4; kc++) {
        bf16x8 v0 = *(const bf16x8*)&qp0[kc*32 + quad*8];
        bf16x8 v1 = *(const bf16x8*)&qp1[kc*32 + quad*8];
#pragma unroll
        for (int j = 0; j < 8; j++) {
          float f0 = bf2f((ushort_t)v0[j]); qv0[kc][j] = f0; ss0 += f0*f0;
          float f1 = bf2f((ushort_t)v1[j]); qv1[kc][j] = f1; ss1 += f1*f1;
        }
      }
      ss0 += __shfl_xor(ss0, 16); ss0 += __shfl_xor(ss0, 32);
      ss1 += __shfl_xor(ss1, 16); ss1 += __shfl_xor(ss1, 32);
      const float sc0 = rsqrtf(ss0*(1.0f/128.0f) + 1e-6f) * 0.08838834764831845f;
      const float sc1 = rsqrtf(ss1*(1.0f/128.0f) + 1e-6f) * 0.08838834764831845f;
#pragma unroll
      for (int kc = 0; kc < 4; kc++) {
        bf16x8 g = *(const bf16x8*)&qgamma[kc*32 + quad*8];
        bf16x8 o0, o1;
#pragma unroll
        for (int j = 0; j < 8; j++) {
          const float gg = bf2f((ushort_t)g[j]);
          o0[j] = (short)f2bf(qv0[kc][j] * sc0 * gg);
          o1[j] = (short)f2bf(qv1[kc][j] * sc1 * gg);
        }
        qf0[kc] = o0; qf1[kc] = o1;
      }
    }

    f32x4 Ob0[8], Ob1[8];
#pragma unroll
    for (int i = 0; i < 8; i++) { Ob0[i] = (f32x4){0.f,0.f,0.f,0.f}; Ob1[i] = (f32x4){0.f,0.f,0.f,0.f}; }
    float l0 = 0.f, l1 = 0.f;

    loadKV(0);
    __syncthreads();          // previous phase's LDS readers done (no-op ph=0)
    writeKV();
    __syncthreads();

    // ---- main loop: tiles 0..2bx (both groups); tile 2bx is grp0's diag ----
    const int ndiag = 2*bx;
    for (int kb = 0; kb <= ndiag; kb++) {
      loadKV(kb+1);                     // tail tile always follows

      f32x4 st0[4], st1[4];
#pragma unroll
      for (int s = 0; s < 4; s++) { st0[s] = (f32x4){0.f,0.f,0.f,0.f}; st1[s] = (f32x4){0.f,0.f,0.f,0.f}; }
#pragma unroll
      for (int s = 0; s < 4; s++) {
        const int row = s*16 + l16;
#pragma unroll
        for (int kc = 0; kc < 4; kc++) {
          const bf16x8 kf = *(const bf16x8*)&Ks[row*128 + (((kc*4 + quad) ^ (row & 15)))*8];
          st0[s] = __builtin_amdgcn_mfma_f32_16x16x32_bf16(kf, qf0[kc], st0[s], 0, 0, 0);
          st1[s] = __builtin_amdgcn_mfma_f32_16x16x32_bf16(kf, qf1[kc], st1[s], 0, 0, 0);
        }
      }

      if (kb == ndiag) l0 += sm(st0, ps0, true);
      else             l0 += sm(st0, ps0, false);
      l1 += sm(st1, ps1, false);

#pragma unroll
      for (int kc = 0; kc < 2; kc++) {
        const bf16x8 pf0 = *(const bf16x8*)&ps0[kc*32 + quad*8];
        const bf16x8 pf1 = *(const bf16x8*)&ps1[kc*32 + quad*8];
#pragma unroll
        for (int dt = 0; dt < 8; dt++) {
          const int d = dt*16 + l16;
          const bf16x8 vf = *(const bf16x8*)&VTs[d*64 + (((kc*4 + quad) ^ (d & 7)))*8];
          Ob0[dt] = __builtin_amdgcn_mfma_f32_16x16x32_bf16(vf, pf0, Ob0[dt], 0, 0, 0);
          Ob1[dt] = __builtin_amdgcn_mfma_f32_16x16x32_bf16(vf, pf1, Ob1[dt], 0, 0, 0);
        }
      }

      // readers-done barrier WITHOUT draining the vmem prefetch
      __builtin_amdgcn_s_waitcnt(0xC07F);   // lgkmcnt(0) only
      __builtin_amdgcn_s_barrier();
      writeKV();
      __syncthreads();
    }

    // ---- tail tile (kb = 2bx+1): group1 only, its diagonal ----
    {
      f32x4 st1[4];
#pragma unroll
      for (int s = 0; s < 4; s++) st1[s] = (f32x4){0.f,0.f,0.f,0.f};
#pragma unroll
      for (int s = 0; s < 4; s++) {
        const int row = s*16 + l16;
#pragma unroll
        for (int kc = 0; kc < 4; kc++) {
          const bf16x8 kf = *(const bf16x8*)&Ks[row*128 + (((kc*4 + quad) ^ (row & 15)))*8];
          st1[s] = __builtin_amdgcn_mfma_f32_16x16x32_bf16(kf, qf1[kc], st1[s], 0, 0, 0);
        }
      }
      l1 += sm(st1, ps1, true);
#pragma unroll
      for (int kc = 0; kc < 2; kc++) {
        const bf16x8 pf1 = *(const bf16x8*)&ps1[kc*32 + quad*8];
#pragma unroll
        for (int dt = 0; dt < 8; dt++) {
          const int d = dt*16 + l16;
          const bf16x8 vf = *(const bf16x8*)&VTs[d*64 + (((kc*4 + quad) ^ (d & 7)))*8];
          Ob1[dt] = __builtin_amdgcn_mfma_f32_16x16x32_bf16(vf, pf1, Ob1[dt], 0, 0, 0);
        }
      }
    }

    l0 += __shfl_xor(l0, 16); l0 += __shfl_xor(l0, 32);
    l1 += __shfl_xor(l1, 16); l1 += __shfl_xor(l1, 32);
    const float inv0 = __builtin_amdgcn_rcpf(l0);
    const float inv1 = __builtin_amdgcn_rcpf(l1);
    ushort_t* op0 = obuf + (bT + qrow0)*2048 + h*128;
    ushort_t* op1 = obuf + (bT + qrow1)*2048 + h*128;
#pragma unroll
    for (int dt = 0; dt < 8; dt++) {
      us4 pk0, pk1;
#pragma unroll
      for (int r = 0; r < 4; r++) {
        pk0[r] = f2bf(Ob0[dt][r] * inv0);
        pk1[r] = f2bf(Ob1[dt][r] * inv1);
      }
      *(us4*)&op0[dt*16 + quad*4] = pk0;
      *(us4*)&op1[dt*16 + quad*4] = pk1;
    }
  }
}

// ---------------------------------------------------------------------------
// Final GEMM C = A @ B^T with f32-or-bf16 output per flag (unchanged).
// ---------------------------------------------------------------------------
__global__ __launch_bounds__(256) void gemm_final(
    const ushort_t* __restrict__ A, const ushort_t* __restrict__ B,
    ushort_t* __restrict__ C, float* __restrict__ Cf, const int* __restrict__ flag)
{
  __shared__ __align__(16) ushort_t As[128*BK];
  __shared__ __align__(16) ushort_t Bs[128*BK];
  const int tid = threadIdx.x;
  const int lane = tid & 63, wave = tid >> 6;
  const int quad = lane >> 4, l16 = lane & 15;
  const int m0 = blockIdx.y * 128, n0 = blockIdx.x * 128;
  const int wm = (wave >> 1) * 64, wn = (wave & 1) * 64;
  const int srow = lane >> 3, sslot = lane & 7;

  f32x4 acc[4][4];
#pragma unroll
  for (int i = 0; i < 4; i++)
#pragma unroll
    for (int j = 0; j < 4; j++) acc[i][j] = (f32x4){0.f,0.f,0.f,0.f};

  for (int k0 = 0; k0 < 2048; k0 += BK) {
    __syncthreads();
#pragma unroll
    for (int i = 0; i < 4; i++) {
      const int r0 = wave*32 + i*8;
      const int row = r0 + srow;
      const int g = (sslot ^ (row & 7)) * 8;
      async16(A + (size_t)(m0 + row)*2048 + k0 + g, &As[r0*64]);
      async16(B + (size_t)(n0 + row)*2048 + k0 + g, &Bs[r0*64]);
    }
    __syncthreads();
#pragma unroll
    for (int kc = 0; kc < 2; kc++) {
      bf16x8 af[4], bfr[4];
#pragma unroll
      for (int i = 0; i < 4; i++) {
        const int ra = wm + i*16 + l16;
        af[i] = *(const bf16x8*)&As[ra*64 + (((kc*4 + quad) ^ (ra & 7)))*8];
        const int rb = wn + i*16 + l16;
        bfr[i] = *(const bf16x8*)&Bs[rb*64 + (((kc*4 + quad) ^ (rb & 7)))*8];
      }
#pragma unroll
      for (int i = 0; i < 4; i++)
#pragma unroll
        for (int j = 0; j < 4; j++)
          acc[i][j] = __builtin_amdgcn_mfma_f32_16x16x32_bf16(af[i], bfr[j], acc[i][j], 0, 0, 0);
    }
  }
  const bool isf = (*flag != 0);
#pragma unroll
  for (int i = 0; i < 4; i++) {
    const int rbase = m0 + wm + i*16 + quad*4;
#pragma unroll
    for (int j = 0; j < 4; j++) {
      const int col = n0 + wn + j*16 + l16;
#pragma unroll
      for (int r = 0; r < 4; r++) {
        if (isf) Cf[(size_t)(rbase + r)*2048 + col] = acc[i][j][r];
        else     C [(size_t)(rbase + r)*2048 + col] = f2bf(acc[i][j][r]);
      }
    }
  }
}

extern "C" void kernel_launch(void* const* d_in, const int* in_sizes, int n_in,
                              void* d_out, int out_size, void* d_ws, size_t ws_size,
                              hipStream_t stream)
{
  int* flag = (int*)d_ws;
  ushort_t* ws = (ushort_t*)d_ws + 8;
  ushort_t* xb  = ws;                        // 8388608 (aliased as obuf later)
  ushort_t* wqb = xb  + (size_t)8388608;     // 4194304
  ushort_t* wkb = wqb + (size_t)4194304;     // 1048576
  ushort_t* wvb = wkb + (size_t)1048576;     // 1048576
  ushort_t* wob = wvb + (size_t)1048576;     // 4194304
  ushort_t* qgb = wob + (size_t)4194304;     // 128
  ushort_t* kgb = qgb + 128;                 // 128
  ushort_t* qbuf = kgb + 128;                // 8388608
  ushort_t* kbuf  = qbuf + (size_t)8388608;  // 2097152
  ushort_t* vtbuf = kbuf + (size_t)2097152;  // 2097152
  ushort_t* obuf = xb;                       // x dead after qkv_gemm

  detect_f32<<<1, 64, 0, stream>>>((const ushort_t*)d_in[1], flag);
  convert_all<<<18433, 256, 0, stream>>>(
      d_in[0], d_in[1], d_in[2], d_in[3], d_in[4], d_in[5], d_in[6],
      xb, wqb, wkb, wvb, wob, qgb, kgb, flag);

  qkv_gemm<<<dim3(24, 32), 256, 0, stream>>>(xb, wqb, wkb, wvb, qbuf, kbuf, vtbuf);
  rmsnorm_rows<<<dim3(1024), 256, 0, stream>>>(kbuf, kgb);
  attn_fused<<<dim3(8, 16, 2), 256, 0, stream>>>(qbuf, kbuf, vtbuf, qgb, obuf);
  gemm_final<<<dim3(16, 32), 256, 0, stream>>>(obuf, wob, (ushort_t*)d_out, (float*)d_out, flag);
}